// Round 6
// baseline (374.871 us; speedup 1.0000x reference)
//
#include <hip/hip_runtime.h>
#include <hip/hip_fp16.h>

#define HIDDEN 128
#define BSHIFT 9                  // 512 nodes per bucket
#define NBUCK_MAX 256

using f32x4 = __attribute__((ext_vector_type(4))) float;
using f16x8 = __attribute__((ext_vector_type(8))) _Float16;

// ---------------------------------------------------------------------------
// CSR build kernels
// ---------------------------------------------------------------------------
__global__ void zero_ints(int* __restrict__ a, int n) {
    int i = blockIdx.x * 256 + threadIdx.x;
    if (i < n) a[i] = 0;
}

__global__ void count_deg(const int* __restrict__ dst, int* __restrict__ deg, int e) {
    int i = blockIdx.x * 256 + threadIdx.x;
    if (i < e) atomicAdd(&deg[dst[i]], 1);
}

__global__ void scan_partial(const int* __restrict__ deg, int* __restrict__ bsum, int n) {
    __shared__ int sd[256];
    const int t = threadIdx.x;
    const int base = blockIdx.x * 1024;
    int s = 0;
    #pragma unroll
    for (int i = 0; i < 4; ++i) {
        int idx = base + t * 4 + i;
        if (idx < n) s += deg[idx];
    }
    sd[t] = s;
    __syncthreads();
    for (int o = 128; o > 0; o >>= 1) {
        if (t < o) sd[t] += sd[t + o];
        __syncthreads();
    }
    if (t == 0) bsum[blockIdx.x] = sd[0];
}

__global__ void scan_bsum(int* __restrict__ bsum, int nb) {
    __shared__ int sd[256];
    const int t = threadIdx.x;
    int v = (t < nb) ? bsum[t] : 0;
    sd[t] = v;
    __syncthreads();
    for (int o = 1; o < 256; o <<= 1) {
        int add = (t >= o) ? sd[t - o] : 0;
        __syncthreads();
        sd[t] += add;
        __syncthreads();
    }
    if (t < nb) bsum[t] = sd[t] - v;
}

__global__ void scan_offsets(const int* __restrict__ deg, const int* __restrict__ bsum,
                             int* __restrict__ offs, int n) {
    __shared__ int sd[256];
    const int t = threadIdx.x;
    const int base = blockIdx.x * 1024;
    int v[4];
    int s = 0;
    #pragma unroll
    for (int i = 0; i < 4; ++i) {
        int idx = base + t * 4 + i;
        v[i] = (idx < n) ? deg[idx] : 0;
        s += v[i];
    }
    sd[t] = s;
    __syncthreads();
    const int mine = s;
    for (int o = 1; o < 256; o <<= 1) {
        int add = (t >= o) ? sd[t - o] : 0;
        __syncthreads();
        sd[t] += add;
        __syncthreads();
    }
    int excl = sd[t] - mine + bsum[blockIdx.x];
    #pragma unroll
    for (int i = 0; i < 4; ++i) {
        int idx = base + t * 4 + i;
        if (idx < n) { offs[idx] = excl; excl += v[i]; }
    }
}

__global__ void init_cursors(const int* __restrict__ offs, int* __restrict__ cursor, int nb) {
    const int b = threadIdx.x;
    if (b < nb) cursor[b] = offs[b << BSHIFT];
}

// P1: LDS-binned partition of edges into bucket-grouped (dst,src) pairs.
__launch_bounds__(256)
__global__ void partition_pairs(const int* __restrict__ src, const int* __restrict__ dst,
                                int* __restrict__ cursor,
                                unsigned long long* __restrict__ pairs, int e) {
    __shared__ int cnt[NBUCK_MAX];
    __shared__ int base[NBUCK_MAX];
    const int t = threadIdx.x;
    const int tile0 = blockIdx.x * 4096;
    cnt[t] = 0;
    __syncthreads();
    int s[16], d[16], b[16];
    #pragma unroll
    for (int j = 0; j < 16; ++j) {
        const int i = tile0 + j * 256 + t;
        if (i < e) {
            d[j] = dst[i];
            s[j] = src[i];
            b[j] = d[j] >> BSHIFT;
            atomicAdd(&cnt[b[j]], 1);
        } else {
            b[j] = -1;
        }
    }
    __syncthreads();
    const int c = cnt[t];
    base[t] = c ? atomicAdd(&cursor[t], c) : 0;
    __syncthreads();
    cnt[t] = 0;
    __syncthreads();
    #pragma unroll
    for (int j = 0; j < 16; ++j) {
        if (b[j] >= 0) {
            const int r = atomicAdd(&cnt[b[j]], 1);
            pairs[(size_t)base[b[j]] + r] =
                ((unsigned long long)(unsigned)d[j] << 32) | (unsigned)s[j];
        }
    }
}

// P2: one block per bucket; csr writes confined to ~32KB region.
__launch_bounds__(256)
__global__ void place_csr(const unsigned long long* __restrict__ pairs,
                          const int* __restrict__ offs,
                          int* __restrict__ csr, int n, int e) {
    __shared__ int cur[1 << BSHIFT];
    const int node0 = blockIdx.x << BSHIFT;
    const int nn = min(1 << BSHIFT, n - node0);
    const int t = threadIdx.x;
    for (int i = t; i < nn; i += 256) cur[i] = offs[node0 + i];
    __syncthreads();
    const int beg = offs[node0];
    const int end = (node0 + nn < n) ? offs[node0 + nn] : e;
    for (int i = beg + t; i < end; i += 256) {
        const unsigned long long pr = pairs[i];
        const int dd = (int)(pr >> 32);
        const int ss = (int)(unsigned)pr;
        const int p = atomicAdd(&cur[dd - node0], 1);
        csr[p] = ss;
    }
}

// ---------------------------------------------------------------------------
// Pack weights into MFMA-fragment-ordered f16 planes:
//   plane0 (offset 0):      Wh  = f16(W)
//   plane1 (offset 32768):  Wls = f16((W - Wh) * 32)   [residual scaled 2^5]
// Buffer = [8 steps][8 ct][64 lane][8]; layer buffers: self steps 0-3, neigh 4-7.
// Lane l of fragment (step, ct): col = ct*16 + (l&15), k = step*32 + (l>>4)*8 + j.
// ---------------------------------------------------------------------------
__global__ void pack_weights(const float* __restrict__ W_t, const float* __restrict__ Ws0,
                             const float* __restrict__ Wn0, const float* __restrict__ Ws1,
                             const float* __restrict__ Wn1,
                             __half* p_t, __half* p_l0, __half* p_l1) {
    const int bid = blockIdx.x;
    const float* W; __half* out; int b0; int S0;
    if (bid < 16)      { W = W_t; out = p_t;  b0 = 0;  S0 = 0; }
    else if (bid < 24) { W = Ws0; out = p_l0; b0 = 16; S0 = 0; }
    else if (bid < 32) { W = Wn0; out = p_l0; b0 = 24; S0 = 4; }
    else if (bid < 40) { W = Ws1; out = p_l1; b0 = 32; S0 = 0; }
    else               { W = Wn1; out = p_l1; b0 = 40; S0 = 4; }
    const int idx = (bid - b0) * 256 + threadIdx.x;   // < K*16  (K = 256 or 128)
    const int step = idx >> 9;
    const int r = idx & 511;
    const int l = r & 63;
    const int col = (r >> 6) * 16 + (l & 15);
    const int k0 = step * 32 + ((l >> 4) << 3);
    const size_t o = (size_t)(S0 + step) * 4096 + (size_t)r * 8;
    #pragma unroll
    for (int j = 0; j < 8; ++j) {
        float f = W[(k0 + j) * HIDDEN + col];
        __half h = __float2half_rn(f);
        out[o + j] = h;
        out[32768 + o + j] = __float2half_rn((f - __half2float(h)) * 32.0f);
    }
}

// ---------------------------------------------------------------------------
// Barrier-free, LDS-free MFMA GEMM.
//   layers    : A exact fp16; acc += A*Wh + (A*2^-5)*Wls          (2 mfma/frag)
//   transform : x split xh + xls (f32 in regs); 3 products         (3 mfma/frag)
// Block 128x128, 4 waves (2x2), wave tile 64x64, 8 K-steps of 32.
// All operands load straight into fragments (A from HBM/L3, W from L2).
// ---------------------------------------------------------------------------
template <bool F32A, bool RELU, bool FINAL>
__launch_bounds__(256, F32A ? 2 : 3)
__global__ void gemm_direct(const void* __restrict__ A0v, const void* __restrict__ A1v,
                            const __half* __restrict__ Wp,
                            const float* __restrict__ bias,
                            const float* __restrict__ wfin,
                            void* __restrict__ outv, int nrows) {
    const int t = threadIdx.x;
    const int lane = t & 63;
    const int w = t >> 6;
    const int wr = w >> 1, wc = w & 1;
    const int blockRow0 = blockIdx.x * 128;
    const int kk = (lane >> 4) << 3;     // element offset within a 32-wide k-step

    int rb[4];
    #pragma unroll
    for (int r4 = 0; r4 < 4; ++r4)
        rb[r4] = min(blockRow0 + wr * 64 + r4 * 16 + (lane & 15), nrows - 1);

    f32x4 acc[4][4];
    #pragma unroll
    for (int i = 0; i < 4; ++i)
        #pragma unroll
        for (int j = 0; j < 4; ++j) acc[i][j] = (f32x4){0.f, 0.f, 0.f, 0.f};

    const _Float16 S = (_Float16)0.03125f;   // 2^-5

    auto LOADA = [&](int step, f16x8 (&a)[4], f16x8 (&ls)[4]) {
        #pragma unroll
        for (int r4 = 0; r4 < 4; ++r4) {
            if constexpr (F32A) {
                const float* p = (const float*)A0v + (size_t)rb[r4] * 256 + step * 32 + kk;
                float4 f0 = *(const float4*)p;
                float4 f1 = *(const float4*)(p + 4);
                float fv[8] = {f0.x, f0.y, f0.z, f0.w, f1.x, f1.y, f1.z, f1.w};
                f16x8 ah, al;
                #pragma unroll
                for (int j = 0; j < 8; ++j) {
                    _Float16 h = (_Float16)fv[j];
                    ah[j] = h;
                    al[j] = (_Float16)((fv[j] - (float)h) * 32.0f);
                }
                a[r4] = ah;
                ls[r4] = al;
            } else {
                const __half* base = (step < 4) ? (const __half*)A0v : (const __half*)A1v;
                a[r4] = *(const f16x8*)(base + (size_t)rb[r4] * HIDDEN + (step & 3) * 32 + kk);
                (void)ls;
            }
        }
    };

    auto STEP = [&](int step, f16x8 (&ac)[4], f16x8 (&sc)[4],
                    f16x8 (&an)[4], f16x8 (&sn)[4]) {
        if (step < 7) LOADA(step + 1, an, sn);           // next-step A in flight
        const __half* wb = Wp + (size_t)step * 4096 + (wc * 4) * 512 + lane * 8;
        f16x8 wh[4], wl[4];
        #pragma unroll
        for (int c4 = 0; c4 < 4; ++c4) {
            wh[c4] = *(const f16x8*)(wb + c4 * 512);
            wl[c4] = *(const f16x8*)(wb + 32768 + c4 * 512);
        }
        f16x8 asr[4];
        #pragma unroll
        for (int r4 = 0; r4 < 4; ++r4) asr[r4] = ac[r4] * S;
        #pragma unroll
        for (int r4 = 0; r4 < 4; ++r4)
            #pragma unroll
            for (int c4 = 0; c4 < 4; ++c4) {
                acc[r4][c4] = __builtin_amdgcn_mfma_f32_16x16x32_f16(ac[r4], wh[c4], acc[r4][c4], 0, 0, 0);
                acc[r4][c4] = __builtin_amdgcn_mfma_f32_16x16x32_f16(asr[r4], wl[c4], acc[r4][c4], 0, 0, 0);
            }
        if constexpr (F32A) {
            f16x8 whs[4];
            #pragma unroll
            for (int c4 = 0; c4 < 4; ++c4) whs[c4] = wh[c4] * S;
            #pragma unroll
            for (int r4 = 0; r4 < 4; ++r4)
                #pragma unroll
                for (int c4 = 0; c4 < 4; ++c4)
                    acc[r4][c4] = __builtin_amdgcn_mfma_f32_16x16x32_f16(sc[r4], whs[c4], acc[r4][c4], 0, 0, 0);
        }
    };

    f16x8 a0[4], a1[4], s0[4], s1[4];
    LOADA(0, a0, s0);
    STEP(0, a0, s0, a1, s1);
    STEP(1, a1, s1, a0, s0);
    STEP(2, a0, s0, a1, s1);
    STEP(3, a1, s1, a0, s0);
    STEP(4, a0, s0, a1, s1);
    STEP(5, a1, s1, a0, s0);
    STEP(6, a0, s0, a1, s1);
    STEP(7, a1, s1, a0, s0);

    // epilogue
    if constexpr (FINAL) {
        __shared__ float red[128][2];
        float wf[4], bc[4];
        #pragma unroll
        for (int c4 = 0; c4 < 4; ++c4) {
            const int col = (wc * 4 + c4) * 16 + (lane & 15);
            wf[c4] = wfin[col];
            bc[c4] = bias[col];
        }
        float part[4][4];
        #pragma unroll
        for (int r4 = 0; r4 < 4; ++r4)
            #pragma unroll
            for (int j = 0; j < 4; ++j) {
                float s = 0.f;
                #pragma unroll
                for (int c4 = 0; c4 < 4; ++c4) {
                    float v = acc[r4][c4][j] + bc[c4];
                    if (RELU) v = fmaxf(v, 0.f);
                    s = fmaf(v, wf[c4], s);
                }
                part[r4][j] = s;
            }
        #pragma unroll
        for (int o = 1; o < 16; o <<= 1)
            #pragma unroll
            for (int r4 = 0; r4 < 4; ++r4)
                #pragma unroll
                for (int j = 0; j < 4; ++j)
                    part[r4][j] += __shfl_xor(part[r4][j], o, 64);
        if ((lane & 15) == 0) {
            #pragma unroll
            for (int r4 = 0; r4 < 4; ++r4)
                #pragma unroll
                for (int j = 0; j < 4; ++j) {
                    const int rl = wr * 64 + r4 * 16 + ((lane >> 4) << 2) + j;
                    red[rl][wc] = part[r4][j];
                }
        }
        __syncthreads();
        if (t < 128) {
            const int r = blockRow0 + t;
            if (r < nrows) ((float*)outv)[r] = red[t][0] + red[t][1];
        }
    } else {
        __half* out = (__half*)outv;
        #pragma unroll
        for (int c4 = 0; c4 < 4; ++c4) {
            const int col = (wc * 4 + c4) * 16 + (lane & 15);
            const float bc = bias[col];
            #pragma unroll
            for (int r4 = 0; r4 < 4; ++r4) {
                const int r0 = blockRow0 + (wr * 4 + r4) * 16 + ((lane >> 4) << 2);
                #pragma unroll
                for (int j = 0; j < 4; ++j) {
                    const int r = r0 + j;
                    if (r < nrows) {
                        float v = acc[r4][c4][j] + bc;
                        if (RELU) v = fmaxf(v, 0.f);
                        out[(size_t)r * HIDDEN + col] = __float2half(v);
                    }
                }
            }
        }
    }
}

// ---------------------------------------------------------------------------
// Neighbor mean over fp16 h. One wave per node; 2 edges per wave-load.
// ---------------------------------------------------------------------------
__global__ void aggregate_h16(const __half* __restrict__ h, const int* __restrict__ offs,
                              const int* __restrict__ deg, const int* __restrict__ csr,
                              __half* __restrict__ agg, int n) {
    const int node = blockIdx.x * 4 + (threadIdx.x >> 6);
    if (node >= n) return;
    const int lane = threadIdx.x & 63;
    const int eh = lane >> 5;           // edge slot (0/1)
    const int c4 = (lane & 31) * 4;     // 4 cols per lane
    const int start = offs[node];
    const int d = deg[node];
    float a0 = 0.f, a1 = 0.f, a2 = 0.f, a3 = 0.f;
    int i = eh;
    for (; i + 6 < d; i += 8) {
        int s[4];
        #pragma unroll
        for (int j = 0; j < 4; ++j) s[j] = csr[start + i + 2 * j];
        #pragma unroll
        for (int j = 0; j < 4; ++j) {
            uint2 raw = *(const uint2*)&h[(size_t)s[j] * HIDDEN + c4];
            float2 f0 = __half22float2(*(__half2*)&raw.x);
            float2 f1 = __half22float2(*(__half2*)&raw.y);
            a0 += f0.x; a1 += f0.y; a2 += f1.x; a3 += f1.y;
        }
    }
    for (; i < d; i += 2) {
        int s0 = csr[start + i];
        uint2 raw = *(const uint2*)&h[(size_t)s0 * HIDDEN + c4];
        float2 f0 = __half22float2(*(__half2*)&raw.x);
        float2 f1 = __half22float2(*(__half2*)&raw.y);
        a0 += f0.x; a1 += f0.y; a2 += f1.x; a3 += f1.y;
    }
    a0 += __shfl_xor(a0, 32, 64);
    a1 += __shfl_xor(a1, 32, 64);
    a2 += __shfl_xor(a2, 32, 64);
    a3 += __shfl_xor(a3, 32, 64);
    if (eh == 0) {
        const float inv = 1.0f / (float)max(d, 1);
        __half2 o0 = __floats2half2_rn(a0 * inv, a1 * inv);
        __half2 o1 = __floats2half2_rn(a2 * inv, a3 * inv);
        uint2 raw;
        raw.x = *(unsigned*)&o0;
        raw.y = *(unsigned*)&o1;
        *(uint2*)&agg[(size_t)node * HIDDEN + c4] = raw;
    }
}

// ---------------------------------------------------------------------------
extern "C" void kernel_launch(void* const* d_in, const int* in_sizes, int n_in,
                              void* d_out, int out_size, void* d_ws, size_t ws_size,
                              hipStream_t stream) {
    const float* x     = (const float*)d_in[0];
    const float* W_t   = (const float*)d_in[1];
    const float* b_t   = (const float*)d_in[2];
    const float* W_s0  = (const float*)d_in[3];
    const float* b_s0  = (const float*)d_in[4];
    const float* W_n0  = (const float*)d_in[5];
    const float* W_s1  = (const float*)d_in[6];
    const float* b_s1  = (const float*)d_in[7];
    const float* W_n1  = (const float*)d_in[8];
    const float* W_fin = (const float*)d_in[9];
    const int*   src   = (const int*)d_in[10];
    const int*   dst   = (const int*)d_in[11];
    float* out = (float*)d_out;

    const int N = in_sizes[0] / 256;   // 100000
    const int E = in_sizes[10];        // 1600000

    size_t off_b = 0;
    auto carve = [&](size_t bytes) {
        size_t cur = off_b;
        off_b = (off_b + bytes + 255) & ~(size_t)255;
        return cur;
    };
    char* base = (char*)d_ws;
    int* deg    = (int*)(base + carve((size_t)N * 4));
    int* offs   = (int*)(base + carve((size_t)N * 4));
    int* bsum   = (int*)(base + carve(1024 * 4));
    int* cursor = (int*)(base + carve(NBUCK_MAX * 4));
    int* csr    = (int*)(base + carve((size_t)E * 4));
    unsigned long long* pairs = (unsigned long long*)(base + carve((size_t)E * 8));
    __half* wp_t  = (__half*)(base + carve((size_t)65536 * 2));
    __half* wp_l0 = (__half*)(base + carve((size_t)65536 * 2));
    __half* wp_l1 = (__half*)(base + carve((size_t)65536 * 2));
    __half* hA  = (__half*)(base + carve((size_t)N * HIDDEN * 2));
    __half* hB  = (__half*)(base + carve((size_t)N * HIDDEN * 2));
    __half* agp = (__half*)(base + carve((size_t)N * HIDDEN * 2));
    (void)ws_size; (void)n_in; (void)out_size;

    const int nbScan = (N + 1023) / 1024;
    const int nBuck  = (N + (1 << BSHIFT) - 1) >> BSHIFT;

    // --- CSR build ---
    hipLaunchKernelGGL(zero_ints, dim3((N + 255) / 256), dim3(256), 0, stream, deg, N);
    hipLaunchKernelGGL(count_deg, dim3((E + 255) / 256), dim3(256), 0, stream, dst, deg, E);
    hipLaunchKernelGGL(scan_partial, dim3(nbScan), dim3(256), 0, stream, deg, bsum, N);
    hipLaunchKernelGGL(scan_bsum, dim3(1), dim3(256), 0, stream, bsum, nbScan);
    hipLaunchKernelGGL(scan_offsets, dim3(nbScan), dim3(256), 0, stream, deg, bsum, offs, N);
    hipLaunchKernelGGL(init_cursors, dim3(1), dim3(256), 0, stream, offs, cursor, nBuck);
    hipLaunchKernelGGL(partition_pairs, dim3((E + 4095) / 4096), dim3(256), 0, stream,
                       src, dst, cursor, pairs, E);
    hipLaunchKernelGGL(place_csr, dim3(nBuck), dim3(256), 0, stream, pairs, offs, csr, N, E);

    // --- weight packing (48 tiny blocks) ---
    hipLaunchKernelGGL(pack_weights, dim3(48), dim3(256), 0, stream,
                       W_t, W_s0, W_n0, W_s1, W_n1, wp_t, wp_l0, wp_l1);

    const int gemmGrid = (N + 127) / 128;
    const int nodeGrid = (N + 3) / 4;

    // h0 = x @ W_t + b_t  (f32 A, in-reg split)
    hipLaunchKernelGGL((gemm_direct<true, false, false>), dim3(gemmGrid), dim3(256), 0, stream,
                       (const void*)x, (const void*)nullptr, wp_t, b_t, (const float*)nullptr,
                       (void*)hA, N);
    // layer 0
    hipLaunchKernelGGL(aggregate_h16, dim3(nodeGrid), dim3(256), 0, stream, hA, offs, deg, csr, agp, N);
    hipLaunchKernelGGL((gemm_direct<false, true, false>), dim3(gemmGrid), dim3(256), 0, stream,
                       (const void*)hA, (const void*)agp, wp_l0, b_s0, (const float*)nullptr,
                       (void*)hB, N);
    // layer 1 + fused final projection
    hipLaunchKernelGGL(aggregate_h16, dim3(nodeGrid), dim3(256), 0, stream, hB, offs, deg, csr, agp, N);
    hipLaunchKernelGGL((gemm_direct<false, true, true>), dim3(gemmGrid), dim3(256), 0, stream,
                       (const void*)hB, (const void*)agp, wp_l1, b_s1, W_fin,
                       (void*)out, N);
}

// Round 7
// 358.584 us; speedup vs baseline: 1.0454x; 1.0454x over previous
//
#include <hip/hip_runtime.h>
#include <hip/hip_fp16.h>

#define HIDDEN 128
#define BSHIFT 9                  // 512 nodes per bucket
#define NBUCK_MAX 256

using f32x4 = __attribute__((ext_vector_type(4))) float;
using f16x8 = __attribute__((ext_vector_type(8))) _Float16;

__device__ __forceinline__ void gload16(const void* g, void* l) {
    __builtin_amdgcn_global_load_lds((const __attribute__((address_space(1))) void*)g,
                                     (__attribute__((address_space(3))) void*)l,
                                     16, 0, 0);
}

// ---------------------------------------------------------------------------
// CSR build kernels
// ---------------------------------------------------------------------------
__global__ void zero_ints(int* __restrict__ a, int n) {
    int i = blockIdx.x * 256 + threadIdx.x;
    if (i < n) a[i] = 0;
}

__global__ void count_deg(const int* __restrict__ dst, int* __restrict__ deg, int e) {
    int i = blockIdx.x * 256 + threadIdx.x;
    if (i < e) atomicAdd(&deg[dst[i]], 1);
}

__global__ void scan_partial(const int* __restrict__ deg, int* __restrict__ bsum, int n) {
    __shared__ int sd[256];
    const int t = threadIdx.x;
    const int base = blockIdx.x * 1024;
    int s = 0;
    #pragma unroll
    for (int i = 0; i < 4; ++i) {
        int idx = base + t * 4 + i;
        if (idx < n) s += deg[idx];
    }
    sd[t] = s;
    __syncthreads();
    for (int o = 128; o > 0; o >>= 1) {
        if (t < o) sd[t] += sd[t + o];
        __syncthreads();
    }
    if (t == 0) bsum[blockIdx.x] = sd[0];
}

__global__ void scan_bsum(int* __restrict__ bsum, int nb) {
    __shared__ int sd[256];
    const int t = threadIdx.x;
    int v = (t < nb) ? bsum[t] : 0;
    sd[t] = v;
    __syncthreads();
    for (int o = 1; o < 256; o <<= 1) {
        int add = (t >= o) ? sd[t - o] : 0;
        __syncthreads();
        sd[t] += add;
        __syncthreads();
    }
    if (t < nb) bsum[t] = sd[t] - v;
}

__global__ void scan_offsets(const int* __restrict__ deg, const int* __restrict__ bsum,
                             int* __restrict__ offs, int n) {
    __shared__ int sd[256];
    const int t = threadIdx.x;
    const int base = blockIdx.x * 1024;
    int v[4];
    int s = 0;
    #pragma unroll
    for (int i = 0; i < 4; ++i) {
        int idx = base + t * 4 + i;
        v[i] = (idx < n) ? deg[idx] : 0;
        s += v[i];
    }
    sd[t] = s;
    __syncthreads();
    const int mine = s;
    for (int o = 1; o < 256; o <<= 1) {
        int add = (t >= o) ? sd[t - o] : 0;
        __syncthreads();
        sd[t] += add;
        __syncthreads();
    }
    int excl = sd[t] - mine + bsum[blockIdx.x];
    #pragma unroll
    for (int i = 0; i < 4; ++i) {
        int idx = base + t * 4 + i;
        if (idx < n) { offs[idx] = excl; excl += v[i]; }
    }
}

__global__ void init_cursors(const int* __restrict__ offs, int* __restrict__ cursor, int nb) {
    const int b = threadIdx.x;
    if (b < nb) cursor[b] = offs[b << BSHIFT];
}

// P1: LDS-binned partition of edges into bucket-grouped (dst,src) pairs.
__launch_bounds__(256)
__global__ void partition_pairs(const int* __restrict__ src, const int* __restrict__ dst,
                                int* __restrict__ cursor,
                                unsigned long long* __restrict__ pairs, int e) {
    __shared__ int cnt[NBUCK_MAX];
    __shared__ int base[NBUCK_MAX];
    const int t = threadIdx.x;
    const int tile0 = blockIdx.x * 4096;
    cnt[t] = 0;
    __syncthreads();
    int s[16], d[16], b[16];
    #pragma unroll
    for (int j = 0; j < 16; ++j) {
        const int i = tile0 + j * 256 + t;
        if (i < e) {
            d[j] = dst[i];
            s[j] = src[i];
            b[j] = d[j] >> BSHIFT;
            atomicAdd(&cnt[b[j]], 1);
        } else {
            b[j] = -1;
        }
    }
    __syncthreads();
    const int c = cnt[t];
    base[t] = c ? atomicAdd(&cursor[t], c) : 0;
    __syncthreads();
    cnt[t] = 0;
    __syncthreads();
    #pragma unroll
    for (int j = 0; j < 16; ++j) {
        if (b[j] >= 0) {
            const int r = atomicAdd(&cnt[b[j]], 1);
            pairs[(size_t)base[b[j]] + r] =
                ((unsigned long long)(unsigned)d[j] << 32) | (unsigned)s[j];
        }
    }
}

// P2: one block per bucket; csr writes confined to ~32KB region.
__launch_bounds__(256)
__global__ void place_csr(const unsigned long long* __restrict__ pairs,
                          const int* __restrict__ offs,
                          int* __restrict__ csr, int n, int e) {
    __shared__ int cur[1 << BSHIFT];
    const int node0 = blockIdx.x << BSHIFT;
    const int nn = min(1 << BSHIFT, n - node0);
    const int t = threadIdx.x;
    for (int i = t; i < nn; i += 256) cur[i] = offs[node0 + i];
    __syncthreads();
    const int beg = offs[node0];
    const int end = (node0 + nn < n) ? offs[node0 + nn] : e;
    for (int i = beg + t; i < end; i += 256) {
        const unsigned long long pr = pairs[i];
        const int dd = (int)(pr >> 32);
        const int ss = (int)(unsigned)pr;
        const int p = atomicAdd(&cur[dd - node0], 1);
        csr[p] = ss;
    }
}

// ---------------------------------------------------------------------------
// Pack weights into MFMA-fragment-ordered f16 planes:
//   plane0 (offset 0):      Wh  = f16(W)
//   plane1 (offset 32768):  Wls = f16((W - Wh) * 32)   [residual scaled 2^5]
// Buffer = [8 steps][8 ct][64 lane][8]; layer buffers: self steps 0-3, neigh 4-7.
// Lane l of fragment (step, ct): col = ct*16 + (l&15), k = step*32 + (l>>4)*8 + j.
// ---------------------------------------------------------------------------
__global__ void pack_weights(const float* __restrict__ W_t, const float* __restrict__ Ws0,
                             const float* __restrict__ Wn0, const float* __restrict__ Ws1,
                             const float* __restrict__ Wn1,
                             __half* p_t, __half* p_l0, __half* p_l1) {
    const int bid = blockIdx.x;
    const float* W; __half* out; int b0; int S0;
    if (bid < 16)      { W = W_t; out = p_t;  b0 = 0;  S0 = 0; }
    else if (bid < 24) { W = Ws0; out = p_l0; b0 = 16; S0 = 0; }
    else if (bid < 32) { W = Wn0; out = p_l0; b0 = 24; S0 = 4; }
    else if (bid < 40) { W = Ws1; out = p_l1; b0 = 32; S0 = 0; }
    else               { W = Wn1; out = p_l1; b0 = 40; S0 = 4; }
    const int idx = (bid - b0) * 256 + threadIdx.x;   // < K*16  (K = 256 or 128)
    const int step = idx >> 9;
    const int r = idx & 511;
    const int l = r & 63;
    const int col = (r >> 6) * 16 + (l & 15);
    const int k0 = step * 32 + ((l >> 4) << 3);
    const size_t o = (size_t)(S0 + step) * 4096 + (size_t)r * 8;
    #pragma unroll
    for (int j = 0; j < 8; ++j) {
        float f = W[(k0 + j) * HIDDEN + col];
        __half h = __float2half_rn(f);
        out[o + j] = h;
        out[32768 + o + j] = __float2half_rn((f - __half2float(h)) * 32.0f);
    }
}

// ---------------------------------------------------------------------------
// Layer GEMM: A = [hA | agp] fp16 (K=128+128). Burst-stage the WHOLE A tile
// (64 KB) via global_load_lds, ONE barrier, then a barrier-free K-loop:
// ds_read_b128 fragments + L2-hot W + MFMA. Emulation: acc += A*Wh + (A*2^-5)*Wls.
// Block 128x128, 4 waves (2x2), wave tile 64x64.
// ---------------------------------------------------------------------------
template <bool RELU, bool FINAL>
__launch_bounds__(256, 2)
__global__ void gemm_h16(const __half* __restrict__ A0, const __half* __restrict__ A1,
                         const __half* __restrict__ Wp,
                         const float* __restrict__ bias,
                         const float* __restrict__ wfin,
                         void* __restrict__ outv, int nrows) {
    __shared__ __align__(16) __half As[8][8][64][8];   // [step][rt][lane][8] = 64 KB

    const int t = threadIdx.x;
    const int lane = t & 63;
    const int w = t >> 6;
    const int wr = w >> 1, wc = w & 1;
    const int blockRow0 = blockIdx.x * 128;
    const int koff = (lane >> 4) << 3;

    // burst-stage: wave w stages rt = 2w, 2w+1 for all 8 steps (16 DMA ops in flight)
    #pragma unroll
    for (int i = 0; i < 2; ++i) {
        const int rt = w * 2 + i;
        const int row = min(blockRow0 + rt * 16 + (lane & 15), nrows - 1);
        #pragma unroll
        for (int step = 0; step < 8; ++step) {
            const __half* src = ((step < 4) ? A0 : A1) + (size_t)row * HIDDEN + (step & 3) * 32 + koff;
            gload16(src, &As[step][rt][0][0]);
        }
    }
    __syncthreads();   // single drain; LDS read-only afterwards

    f32x4 acc[4][4];
    #pragma unroll
    for (int i = 0; i < 4; ++i)
        #pragma unroll
        for (int j = 0; j < 4; ++j) acc[i][j] = (f32x4){0.f, 0.f, 0.f, 0.f};

    const _Float16 S = (_Float16)0.03125f;   // 2^-5

    #pragma unroll
    for (int step = 0; step < 8; ++step) {
        const __half* wb = Wp + (size_t)step * 4096 + (wc * 4) * 512 + lane * 8;
        f16x8 wh[4], wl[4];
        #pragma unroll
        for (int c4 = 0; c4 < 4; ++c4) {
            wh[c4] = *(const f16x8*)(wb + c4 * 512);
            wl[c4] = *(const f16x8*)(wb + 32768 + c4 * 512);
        }
        f16x8 a[4], asr[4];
        #pragma unroll
        for (int r4 = 0; r4 < 4; ++r4) {
            a[r4] = *(const f16x8*)&As[step][wr * 4 + r4][lane][0];
            asr[r4] = a[r4] * S;
        }
        #pragma unroll
        for (int r4 = 0; r4 < 4; ++r4)
            #pragma unroll
            for (int c4 = 0; c4 < 4; ++c4) {
                acc[r4][c4] = __builtin_amdgcn_mfma_f32_16x16x32_f16(a[r4], wh[c4], acc[r4][c4], 0, 0, 0);
                acc[r4][c4] = __builtin_amdgcn_mfma_f32_16x16x32_f16(asr[r4], wl[c4], acc[r4][c4], 0, 0, 0);
            }
    }

    // epilogue
    if constexpr (FINAL) {
        __shared__ float red[128][2];
        float wf[4], bc[4];
        #pragma unroll
        for (int c4 = 0; c4 < 4; ++c4) {
            const int col = (wc * 4 + c4) * 16 + (lane & 15);
            wf[c4] = wfin[col];
            bc[c4] = bias[col];
        }
        float part[4][4];
        #pragma unroll
        for (int r4 = 0; r4 < 4; ++r4)
            #pragma unroll
            for (int j = 0; j < 4; ++j) {
                float s = 0.f;
                #pragma unroll
                for (int c4 = 0; c4 < 4; ++c4) {
                    float v = acc[r4][c4][j] + bc[c4];
                    if (RELU) v = fmaxf(v, 0.f);
                    s = fmaf(v, wf[c4], s);
                }
                part[r4][j] = s;
            }
        #pragma unroll
        for (int o = 1; o < 16; o <<= 1)
            #pragma unroll
            for (int r4 = 0; r4 < 4; ++r4)
                #pragma unroll
                for (int j = 0; j < 4; ++j)
                    part[r4][j] += __shfl_xor(part[r4][j], o, 64);
        if ((lane & 15) == 0) {
            #pragma unroll
            for (int r4 = 0; r4 < 4; ++r4)
                #pragma unroll
                for (int j = 0; j < 4; ++j) {
                    const int rl = wr * 64 + r4 * 16 + ((lane >> 4) << 2) + j;
                    red[rl][wc] = part[r4][j];
                }
        }
        __syncthreads();
        if (t < 128) {
            const int r = blockRow0 + t;
            if (r < nrows) ((float*)outv)[r] = red[t][0] + red[t][1];
        }
    } else {
        __half* out = (__half*)outv;
        #pragma unroll
        for (int c4 = 0; c4 < 4; ++c4) {
            const int col = (wc * 4 + c4) * 16 + (lane & 15);
            const float bc = bias[col];
            #pragma unroll
            for (int r4 = 0; r4 < 4; ++r4) {
                const int r0 = blockRow0 + (wr * 4 + r4) * 16 + ((lane >> 4) << 2);
                #pragma unroll
                for (int j = 0; j < 4; ++j) {
                    const int r = r0 + j;
                    if (r < nrows) {
                        float v = acc[r4][c4][j] + bc;
                        if (RELU) v = fmaxf(v, 0.f);
                        out[(size_t)r * HIDDEN + col] = __float2half(v);
                    }
                }
            }
        }
    }
}

// ---------------------------------------------------------------------------
// Transform GEMM: A = x (f32, K=256). Two 64 KB burst phases (steps 0-3, 4-7):
// stage f32 tile via global_load_lds, barrier, compute (split to f16 at read).
// Emulation (3 products): acc += ah*Wh + (ah*2^-5)*Wls + al*(Wh*2^-5).
// ---------------------------------------------------------------------------
__launch_bounds__(256, 2)
__global__ void gemm_f32(const float* __restrict__ X, const __half* __restrict__ Wp,
                         const float* __restrict__ bias,
                         __half* __restrict__ outp, int nrows) {
    __shared__ __align__(16) float Xs[4][8][2][64][4];   // [s4][rt][half][lane][4] = 64 KB

    const int t = threadIdx.x;
    const int lane = t & 63;
    const int w = t >> 6;
    const int wr = w >> 1, wc = w & 1;
    const int blockRow0 = blockIdx.x * 128;
    const int koff = (lane >> 4) << 3;

    f32x4 acc[4][4];
    #pragma unroll
    for (int i = 0; i < 4; ++i)
        #pragma unroll
        for (int j = 0; j < 4; ++j) acc[i][j] = (f32x4){0.f, 0.f, 0.f, 0.f};

    const _Float16 S = (_Float16)0.03125f;   // 2^-5

    #pragma unroll 1
    for (int ph = 0; ph < 2; ++ph) {
        // burst-stage 4 steps (f32): 16 DMA ops per wave
        #pragma unroll
        for (int i = 0; i < 2; ++i) {
            const int rt = w * 2 + i;
            const int row = min(blockRow0 + rt * 16 + (lane & 15), nrows - 1);
            #pragma unroll
            for (int s4 = 0; s4 < 4; ++s4) {
                const float* src = X + (size_t)row * 256 + (ph * 4 + s4) * 32 + koff;
                gload16(src,     &Xs[s4][rt][0][0][0]);
                gload16(src + 4, &Xs[s4][rt][1][0][0]);
            }
        }
        __syncthreads();   // drain burst

        #pragma unroll
        for (int s4 = 0; s4 < 4; ++s4) {
            const int step = ph * 4 + s4;
            const __half* wb = Wp + (size_t)step * 4096 + (wc * 4) * 512 + lane * 8;
            f16x8 wh[4], wl[4], whs[4];
            #pragma unroll
            for (int c4 = 0; c4 < 4; ++c4) {
                wh[c4] = *(const f16x8*)(wb + c4 * 512);
                wl[c4] = *(const f16x8*)(wb + 32768 + c4 * 512);
                whs[c4] = wh[c4] * S;
            }
            f16x8 ah[4], al[4], asr[4];
            #pragma unroll
            for (int r4 = 0; r4 < 4; ++r4) {
                f32x4 x0 = *(const f32x4*)&Xs[s4][wr * 4 + r4][0][lane][0];
                f32x4 x1 = *(const f32x4*)&Xs[s4][wr * 4 + r4][1][lane][0];
                float fv[8] = {x0[0], x0[1], x0[2], x0[3], x1[0], x1[1], x1[2], x1[3]};
                f16x8 h, l;
                #pragma unroll
                for (int j = 0; j < 8; ++j) {
                    _Float16 hj = (_Float16)fv[j];
                    h[j] = hj;
                    l[j] = (_Float16)((fv[j] - (float)hj) * 32.0f);
                }
                ah[r4] = h;
                al[r4] = l;
                asr[r4] = h * S;
            }
            #pragma unroll
            for (int r4 = 0; r4 < 4; ++r4)
                #pragma unroll
                for (int c4 = 0; c4 < 4; ++c4) {
                    acc[r4][c4] = __builtin_amdgcn_mfma_f32_16x16x32_f16(ah[r4], wh[c4], acc[r4][c4], 0, 0, 0);
                    acc[r4][c4] = __builtin_amdgcn_mfma_f32_16x16x32_f16(asr[r4], wl[c4], acc[r4][c4], 0, 0, 0);
                    acc[r4][c4] = __builtin_amdgcn_mfma_f32_16x16x32_f16(al[r4], whs[c4], acc[r4][c4], 0, 0, 0);
                }
        }
        __syncthreads();   // protect Xs before next phase restage
    }

    // epilogue: bias, fp16 h store
    #pragma unroll
    for (int c4 = 0; c4 < 4; ++c4) {
        const int col = (wc * 4 + c4) * 16 + (lane & 15);
        const float bc = bias[col];
        #pragma unroll
        for (int r4 = 0; r4 < 4; ++r4) {
            const int r0 = blockRow0 + (wr * 4 + r4) * 16 + ((lane >> 4) << 2);
            #pragma unroll
            for (int j = 0; j < 4; ++j) {
                const int r = r0 + j;
                if (r < nrows)
                    outp[(size_t)r * HIDDEN + col] = __float2half(acc[r4][c4][j] + bc);
            }
        }
    }
}

// ---------------------------------------------------------------------------
// Neighbor mean over fp16 h. One wave per node; 2 edges per wave-load.
// ---------------------------------------------------------------------------
__global__ void aggregate_h16(const __half* __restrict__ h, const int* __restrict__ offs,
                              const int* __restrict__ deg, const int* __restrict__ csr,
                              __half* __restrict__ agg, int n) {
    const int node = blockIdx.x * 4 + (threadIdx.x >> 6);
    if (node >= n) return;
    const int lane = threadIdx.x & 63;
    const int eh = lane >> 5;           // edge slot (0/1)
    const int c4 = (lane & 31) * 4;     // 4 cols per lane
    const int start = offs[node];
    const int d = deg[node];
    float a0 = 0.f, a1 = 0.f, a2 = 0.f, a3 = 0.f;
    int i = eh;
    for (; i + 6 < d; i += 8) {
        int s[4];
        #pragma unroll
        for (int j = 0; j < 4; ++j) s[j] = csr[start + i + 2 * j];
        #pragma unroll
        for (int j = 0; j < 4; ++j) {
            uint2 raw = *(const uint2*)&h[(size_t)s[j] * HIDDEN + c4];
            float2 f0 = __half22float2(*(__half2*)&raw.x);
            float2 f1 = __half22float2(*(__half2*)&raw.y);
            a0 += f0.x; a1 += f0.y; a2 += f1.x; a3 += f1.y;
        }
    }
    for (; i < d; i += 2) {
        int s0 = csr[start + i];
        uint2 raw = *(const uint2*)&h[(size_t)s0 * HIDDEN + c4];
        float2 f0 = __half22float2(*(__half2*)&raw.x);
        float2 f1 = __half22float2(*(__half2*)&raw.y);
        a0 += f0.x; a1 += f0.y; a2 += f1.x; a3 += f1.y;
    }
    a0 += __shfl_xor(a0, 32, 64);
    a1 += __shfl_xor(a1, 32, 64);
    a2 += __shfl_xor(a2, 32, 64);
    a3 += __shfl_xor(a3, 32, 64);
    if (eh == 0) {
        const float inv = 1.0f / (float)max(d, 1);
        __half2 o0 = __floats2half2_rn(a0 * inv, a1 * inv);
        __half2 o1 = __floats2half2_rn(a2 * inv, a3 * inv);
        uint2 raw;
        raw.x = *(unsigned*)&o0;
        raw.y = *(unsigned*)&o1;
        *(uint2*)&agg[(size_t)node * HIDDEN + c4] = raw;
    }
}

// ---------------------------------------------------------------------------
extern "C" void kernel_launch(void* const* d_in, const int* in_sizes, int n_in,
                              void* d_out, int out_size, void* d_ws, size_t ws_size,
                              hipStream_t stream) {
    const float* x     = (const float*)d_in[0];
    const float* W_t   = (const float*)d_in[1];
    const float* b_t   = (const float*)d_in[2];
    const float* W_s0  = (const float*)d_in[3];
    const float* b_s0  = (const float*)d_in[4];
    const float* W_n0  = (const float*)d_in[5];
    const float* W_s1  = (const float*)d_in[6];
    const float* b_s1  = (const float*)d_in[7];
    const float* W_n1  = (const float*)d_in[8];
    const float* W_fin = (const float*)d_in[9];
    const int*   src   = (const int*)d_in[10];
    const int*   dst   = (const int*)d_in[11];
    float* out = (float*)d_out;

    const int N = in_sizes[0] / 256;   // 100000
    const int E = in_sizes[10];        // 1600000

    size_t off_b = 0;
    auto carve = [&](size_t bytes) {
        size_t cur = off_b;
        off_b = (off_b + bytes + 255) & ~(size_t)255;
        return cur;
    };
    char* base = (char*)d_ws;
    int* deg    = (int*)(base + carve((size_t)N * 4));
    int* offs   = (int*)(base + carve((size_t)N * 4));
    int* bsum   = (int*)(base + carve(1024 * 4));
    int* cursor = (int*)(base + carve(NBUCK_MAX * 4));
    int* csr    = (int*)(base + carve((size_t)E * 4));
    unsigned long long* pairs = (unsigned long long*)(base + carve((size_t)E * 8));
    __half* wp_t  = (__half*)(base + carve((size_t)65536 * 2));
    __half* wp_l0 = (__half*)(base + carve((size_t)65536 * 2));
    __half* wp_l1 = (__half*)(base + carve((size_t)65536 * 2));
    __half* hA  = (__half*)(base + carve((size_t)N * HIDDEN * 2));
    __half* hB  = (__half*)(base + carve((size_t)N * HIDDEN * 2));
    __half* agp = (__half*)(base + carve((size_t)N * HIDDEN * 2));
    (void)ws_size; (void)n_in; (void)out_size;

    const int nbScan = (N + 1023) / 1024;
    const int nBuck  = (N + (1 << BSHIFT) - 1) >> BSHIFT;

    // --- CSR build ---
    hipLaunchKernelGGL(zero_ints, dim3((N + 255) / 256), dim3(256), 0, stream, deg, N);
    hipLaunchKernelGGL(count_deg, dim3((E + 255) / 256), dim3(256), 0, stream, dst, deg, E);
    hipLaunchKernelGGL(scan_partial, dim3(nbScan), dim3(256), 0, stream, deg, bsum, N);
    hipLaunchKernelGGL(scan_bsum, dim3(1), dim3(256), 0, stream, bsum, nbScan);
    hipLaunchKernelGGL(scan_offsets, dim3(nbScan), dim3(256), 0, stream, deg, bsum, offs, N);
    hipLaunchKernelGGL(init_cursors, dim3(1), dim3(256), 0, stream, offs, cursor, nBuck);
    hipLaunchKernelGGL(partition_pairs, dim3((E + 4095) / 4096), dim3(256), 0, stream,
                       src, dst, cursor, pairs, E);
    hipLaunchKernelGGL(place_csr, dim3(nBuck), dim3(256), 0, stream, pairs, offs, csr, N, E);

    // --- weight packing (48 tiny blocks) ---
    hipLaunchKernelGGL(pack_weights, dim3(48), dim3(256), 0, stream,
                       W_t, W_s0, W_n0, W_s1, W_n1, wp_t, wp_l0, wp_l1);

    const int gemmGrid = (N + 127) / 128;
    const int nodeGrid = (N + 3) / 4;

    // h0 = x @ W_t + b_t
    hipLaunchKernelGGL(gemm_f32, dim3(gemmGrid), dim3(256), 0, stream,
                       x, wp_t, b_t, hA, N);
    // layer 0
    hipLaunchKernelGGL(aggregate_h16, dim3(nodeGrid), dim3(256), 0, stream, hA, offs, deg, csr, agp, N);
    hipLaunchKernelGGL((gemm_h16<true, false>), dim3(gemmGrid), dim3(256), 0, stream,
                       hA, agp, wp_l0, b_s0, (const float*)nullptr, (void*)hB, N);
    // layer 1 + fused final projection
    hipLaunchKernelGGL(aggregate_h16, dim3(nodeGrid), dim3(256), 0, stream, hB, offs, deg, csr, agp, N);
    hipLaunchKernelGGL((gemm_h16<true, true>), dim3(gemmGrid), dim3(256), 0, stream,
                       hB, agp, wp_l1, b_s1, W_fin, (void*)out, N);
}